// Round 2
// baseline (262.613 us; speedup 1.0000x reference)
//
#include <hip/hip_runtime.h>

#define NSEQ 4096
#define CHN 256

typedef __attribute__((ext_vector_type(8))) short short8;
typedef __attribute__((ext_vector_type(4))) float f32x4;
typedef __attribute__((ext_vector_type(4))) unsigned short us4;
typedef unsigned short u16;

// fp32 -> bf16 round-to-nearest-even
__device__ __forceinline__ u16 f2b(float f) {
  unsigned u = __builtin_bit_cast(unsigned, f);
  unsigned r = (u + 0x7fffu + ((u >> 16) & 1u)) >> 16;
  return (u16)r;
}
__device__ __forceinline__ float b2f(u16 h) {
  unsigned u = ((unsigned)h) << 16;
  return __builtin_bit_cast(float, u);
}

// ws layout in u16 elements
#define QH_OFF   0u          // [B][N][32]  theta^T hi (pre-scaled by log2e)
#define QL_OFF   524288u     // [B][N][32]  theta^T lo
#define KH_OFF   1048576u    // [B][N][32]  phi^T hi
#define KL_OFF   1572864u    // [B][N][32]  phi^T lo
#define V_OFF    2097152u    // [B][128][N] g
#define WQKH_OFF 4194304u    // [64][256]   (Wt*log2e | Wp) hi
#define WQKL_OFF 4210688u    // [64][256]   (Wt*log2e | Wp) lo
#define WG_OFF   4227072u    // [128][256]  Wg
#define WO_OFF   4259840u    // [256][128]  Wo

// ---------------- kernel 0: weight prep (fp32 -> bf16 / hi+lo) ----------------
__global__ __launch_bounds__(256) void prep_weights(
    const float* __restrict__ Wt, const float* __restrict__ Wp,
    const float* __restrict__ Wg, const float* __restrict__ Wo,
    u16* __restrict__ Wqkh, u16* __restrict__ Wqkl,
    u16* __restrict__ Wgb, u16* __restrict__ Wob) {
  int gid = blockIdx.x * 256 + threadIdx.x;  // 80 blocks -> 20480 threads
  if (gid < 4096) {                          // 64*256/4 float4 tasks, hi/lo split
    int row = gid >> 6;
    int c = (gid & 63) * 4;
    const float* src;
    float scale = 1.0f;
    if (row < 32) { src = Wt + row * 256; scale = 1.44269504088896340736f; }
    else          { src = Wp + (row - 32) * 256; }
    float4 v = *(const float4*)(src + c);
    float w0 = v.x * scale, w1 = v.y * scale, w2 = v.z * scale, w3 = v.w * scale;
    us4 hi = { f2b(w0), f2b(w1), f2b(w2), f2b(w3) };
    us4 lo = { f2b(w0 - b2f(hi[0])), f2b(w1 - b2f(hi[1])),
               f2b(w2 - b2f(hi[2])), f2b(w3 - b2f(hi[3])) };
    *(us4*)(Wqkh + row * 256 + c) = hi;
    *(us4*)(Wqkl + row * 256 + c) = lo;
  } else if (gid < 12288) {                  // Wg: 128*256/4 float4 tasks
    int g = (gid - 4096) * 4;
    float4 v = *(const float4*)(Wg + g);
    us4 o = { f2b(v.x), f2b(v.y), f2b(v.z), f2b(v.w) };
    *(us4*)(Wgb + g) = o;
  } else {                                   // Wo: 256*128/4 float4 tasks
    int g = (gid - 12288) * 4;
    float4 v = *(const float4*)(Wo + g);
    us4 o = { f2b(v.x), f2b(v.y), f2b(v.z), f2b(v.w) };
    *(us4*)(Wob + g) = o;
  }
}

// ---------------- kernel 1: QKV projection (MFMA, hi/lo for theta/phi) ----------------
__global__ __launch_bounds__(256) void proj_qkv(
    const float* __restrict__ x,
    const u16* __restrict__ Wqkh, const u16* __restrict__ Wqkl,
    const u16* __restrict__ Wgb,
    u16* __restrict__ QbH, u16* __restrict__ QbL,
    u16* __restrict__ KbH, u16* __restrict__ KbL,
    u16* __restrict__ Vb) {
  int tid = threadIdx.x;
  int wave = tid >> 6, lane = tid & 63;
  int l15 = lane & 15, quad = lane >> 4;
  int b = blockIdx.x >> 6;
  int n0 = (blockIdx.x & 63) * 64;
  int pos = n0 + wave * 16 + l15;
  const float* xb = x + (size_t)b * CHN * NSEQ;

  // A-frags: x^T[pos][c], lane holds c = quad*8+j; hi/lo bf16 split of x
  short8 ahi[8], alo[8];
#pragma unroll
  for (int kc = 0; kc < 8; kc++) {
#pragma unroll
    for (int j = 0; j < 8; j++) {
      int c = kc * 32 + quad * 8 + j;
      float xv = xb[(size_t)c * NSEQ + pos];
      u16 hi = f2b(xv);
      ahi[kc][j] = (short)hi;
      alo[kc][j] = (short)f2b(xv - b2f(hi));
    }
  }
  f32x4 accqk[4];
  f32x4 accg[8];
#pragma unroll
  for (int ot = 0; ot < 4; ot++) accqk[ot] = (f32x4){0.f, 0.f, 0.f, 0.f};
#pragma unroll
  for (int ot = 0; ot < 8; ot++) accg[ot] = (f32x4){0.f, 0.f, 0.f, 0.f};

#pragma unroll
  for (int kc = 0; kc < 8; kc++) {
#pragma unroll
    for (int ot = 0; ot < 4; ot++) {
      size_t off = (size_t)(ot * 16 + l15) * 256 + kc * 32 + quad * 8;
      short8 bh = *(const short8*)(Wqkh + off);
      short8 bl = *(const short8*)(Wqkl + off);
      accqk[ot] = __builtin_amdgcn_mfma_f32_16x16x32_bf16(alo[kc], bh, accqk[ot], 0, 0, 0);
      accqk[ot] = __builtin_amdgcn_mfma_f32_16x16x32_bf16(ahi[kc], bl, accqk[ot], 0, 0, 0);
      accqk[ot] = __builtin_amdgcn_mfma_f32_16x16x32_bf16(ahi[kc], bh, accqk[ot], 0, 0, 0);
    }
#pragma unroll
    for (int ot = 0; ot < 8; ot++) {
      short8 bg = *(const short8*)(Wgb + (size_t)(ot * 16 + l15) * 256 + kc * 32 + quad * 8);
      accg[ot] = __builtin_amdgcn_mfma_f32_16x16x32_bf16(ahi[kc], bg, accg[ot], 0, 0, 0);
    }
  }
  // C-layout: row(pos) = quad*4+r, col(oc) = l15 + 16*ot
  int nbase = n0 + wave * 16 + quad * 4;
#pragma unroll
  for (int ot = 0; ot < 4; ot++) {   // ot 0,1 = theta -> Q; ot 2,3 = phi -> K
#pragma unroll
    for (int r = 0; r < 4; r++) {
      float v = accqk[ot][r];
      u16 hi = f2b(v);
      u16 lo = f2b(v - b2f(hi));
      size_t nrow = (size_t)(b * NSEQ + nbase + r) * 32 + (ot & 1) * 16 + l15;
      if (ot < 2) { QbH[nrow] = hi; QbL[nrow] = lo; }
      else        { KbH[nrow] = hi; KbL[nrow] = lo; }
    }
  }
#pragma unroll
  for (int ot = 0; ot < 8; ot++) {   // g -> Vb [b][128][N]
    int c = ot * 16 + l15;
    us4 pk = { f2b(accg[ot][0]), f2b(accg[ot][1]), f2b(accg[ot][2]), f2b(accg[ot][3]) };
    *(us4*)(Vb + (size_t)(b * 128 + c) * NSEQ + nbase) = pk;
  }
}

// ---------------- kernel 2: fused flash attention + Wo + epilogue ----------------
__global__ __launch_bounds__(256) void flash_attn(
    const u16* __restrict__ QbH, const u16* __restrict__ QbL,
    const u16* __restrict__ KbH, const u16* __restrict__ KbL,
    const u16* __restrict__ Vb, const u16* __restrict__ Wob,
    const float* __restrict__ x, const float* __restrict__ gammap,
    float* __restrict__ out) {
  __shared__ alignas(16) u16 P_lds[4][16][40];
  __shared__ alignas(16) u16 A_lds[4][16][136];
  int tid = threadIdx.x;
  int wave = tid >> 6, lane = tid & 63;
  int l15 = lane & 15, quad = lane >> 4;
  int b = blockIdx.y;
  int n0 = blockIdx.x * 64;
  int nqb = n0 + wave * 16;

  size_t qoff = (size_t)(b * NSEQ + nqb + l15) * 32 + quad * 8;
  short8 qh = *(const short8*)(QbH + qoff);
  short8 ql = *(const short8*)(QbL + qoff);
  const u16* KpH = KbH + (size_t)b * NSEQ * 32;
  const u16* KpL = KbL + (size_t)b * NSEQ * 32;
  const u16* Vp = Vb + (size_t)b * 128 * NSEQ + (size_t)l15 * NSEQ + quad * 8;

  f32x4 acc[8];
#pragma unroll
  for (int vt = 0; vt < 8; vt++) acc[vt] = (f32x4){0.f, 0.f, 0.f, 0.f};
  float lsum = 0.f;

  // prefetch chunk m0 = 0
  short8 kh0 = *(const short8*)(KpH + (size_t)l15 * 32 + quad * 8);
  short8 kh1 = *(const short8*)(KpH + (size_t)(16 + l15) * 32 + quad * 8);
  short8 kl0 = *(const short8*)(KpL + (size_t)l15 * 32 + quad * 8);
  short8 kl1 = *(const short8*)(KpL + (size_t)(16 + l15) * 32 + quad * 8);
  short8 vf[8];
#pragma unroll
  for (int vt = 0; vt < 8; vt++) vf[vt] = *(const short8*)(Vp + (size_t)vt * 16 * NSEQ);

  for (int m0 = 0; m0 < NSEQ; m0 += 32) {
    int mn = (m0 + 32) & (NSEQ - 1);  // wraps harmlessly on last iter
    short8 nkh0 = *(const short8*)(KpH + (size_t)(mn + l15) * 32 + quad * 8);
    short8 nkh1 = *(const short8*)(KpH + (size_t)(mn + 16 + l15) * 32 + quad * 8);
    short8 nkl0 = *(const short8*)(KpL + (size_t)(mn + l15) * 32 + quad * 8);
    short8 nkl1 = *(const short8*)(KpL + (size_t)(mn + 16 + l15) * 32 + quad * 8);
    short8 nvf[8];
#pragma unroll
    for (int vt = 0; vt < 8; vt++)
      nvf[vt] = *(const short8*)(Vp + (size_t)vt * 16 * NSEQ + mn);

    // S^T[mk][nq] = K[mk][c] . Q^T[c][nq]  (hi/lo split; small terms first)
    f32x4 zero = (f32x4){0.f, 0.f, 0.f, 0.f};
    f32x4 s0 = __builtin_amdgcn_mfma_f32_16x16x32_bf16(kl0, qh, zero, 0, 0, 0);
    s0 = __builtin_amdgcn_mfma_f32_16x16x32_bf16(kh0, ql, s0, 0, 0, 0);
    s0 = __builtin_amdgcn_mfma_f32_16x16x32_bf16(kh0, qh, s0, 0, 0, 0);
    f32x4 s1 = __builtin_amdgcn_mfma_f32_16x16x32_bf16(kl1, qh, zero, 0, 0, 0);
    s1 = __builtin_amdgcn_mfma_f32_16x16x32_bf16(kh1, ql, s1, 0, 0, 0);
    s1 = __builtin_amdgcn_mfma_f32_16x16x32_bf16(kh1, qh, s1, 0, 0, 0);

    // p = 2^s ; C-layout: lane holds rows mk = quad*4+r (+16), col nq = l15
    us4 p0, p1;
#pragma unroll
    for (int r = 0; r < 4; r++) {
      float e0 = exp2f(s0[r]);
      float e1 = exp2f(s1[r]);
      lsum += e0 + e1;
      p0[r] = f2b(e0);
      p1[r] = f2b(e1);
    }
    // transpose to A-layout via per-wave LDS (no barrier needed)
    *(us4*)&P_lds[wave][l15][quad * 4] = p0;
    *(us4*)&P_lds[wave][l15][16 + quad * 4] = p1;
    short8 af = *(const short8*)&P_lds[wave][l15][quad * 8];
#pragma unroll
    for (int vt = 0; vt < 8; vt++)
      acc[vt] = __builtin_amdgcn_mfma_f32_16x16x32_bf16(af, vf[vt], acc[vt], 0, 0, 0);

    kh0 = nkh0; kh1 = nkh1; kl0 = nkl0; kl1 = nkl1;
#pragma unroll
    for (int vt = 0; vt < 8; vt++) vf[vt] = nvf[vt];
  }

  // row sums (per nq = l15, replicated across quads)
  lsum += __shfl_xor(lsum, 16);
  lsum += __shfl_xor(lsum, 32);
  float rinv = 1.0f / lsum;
  float rr[4];
#pragma unroll
  for (int r = 0; r < 4; r++) rr[r] = __shfl(rinv, quad * 4 + r);

  // attn^T[nq][vc] (normalized, bf16) into LDS; acc rows are nq = quad*4+r
#pragma unroll
  for (int vt = 0; vt < 8; vt++)
#pragma unroll
    for (int r = 0; r < 4; r++)
      A_lds[wave][quad * 4 + r][vt * 16 + l15] = f2b(acc[vt][r] * rr[r]);

  // Wo GEMM: D[oc, pos] = Wo[oc][vc] . attn[vc][pos]
  short8 bfr[4];
#pragma unroll
  for (int kc = 0; kc < 4; kc++)
    bfr[kc] = *(const short8*)&A_lds[wave][l15][kc * 32 + quad * 8];

  f32x4 oacc[16];
#pragma unroll
  for (int mt = 0; mt < 16; mt++) oacc[mt] = (f32x4){0.f, 0.f, 0.f, 0.f};
#pragma unroll
  for (int mt = 0; mt < 16; mt++) {
#pragma unroll
    for (int kc = 0; kc < 4; kc++) {
      short8 wf = *(const short8*)(Wob + (size_t)(mt * 16 + l15) * 128 + kc * 32 + quad * 8);
      oacc[mt] = __builtin_amdgcn_mfma_f32_16x16x32_bf16(wf, bfr[kc], oacc[mt], 0, 0, 0);
    }
  }
  float gamma = *gammap;
#pragma unroll
  for (int mt = 0; mt < 16; mt++) {
#pragma unroll
    for (int r = 0; r < 4; r++) {
      int oc = mt * 16 + quad * 4 + r;
      size_t idx = ((size_t)b * CHN + oc) * NSEQ + n0 + wave * 16 + l15;
      out[idx] = gamma * oacc[mt][r] + x[idx];
    }
  }
}

extern "C" void kernel_launch(void* const* d_in, const int* in_sizes, int n_in,
                              void* d_out, int out_size, void* d_ws, size_t ws_size,
                              hipStream_t stream) {
  const float* x  = (const float*)d_in[0];
  const float* Wt = (const float*)d_in[1];
  const float* Wp = (const float*)d_in[2];
  const float* Wg = (const float*)d_in[3];
  const float* Wo = (const float*)d_in[4];
  const float* gm = (const float*)d_in[5];
  float* out = (float*)d_out;
  u16* ws = (u16*)d_ws;
  u16* QbH  = ws + QH_OFF;
  u16* QbL  = ws + QL_OFF;
  u16* KbH  = ws + KH_OFF;
  u16* KbL  = ws + KL_OFF;
  u16* Vb   = ws + V_OFF;
  u16* Wqkh = ws + WQKH_OFF;
  u16* Wqkl = ws + WQKL_OFF;
  u16* Wgb  = ws + WG_OFF;
  u16* Wob  = ws + WO_OFF;

  prep_weights<<<80, 256, 0, stream>>>(Wt, Wp, Wg, Wo, Wqkh, Wqkl, Wgb, Wob);
  proj_qkv<<<256, 256, 0, stream>>>(x, Wqkh, Wqkl, Wgb, QbH, QbL, KbH, KbL, Vb);
  flash_attn<<<dim3(64, 4), 256, 0, stream>>>(QbH, QbL, KbH, KbL, Vb, Wob, x, gm, out);
}

// Round 3
// 181.097 us; speedup vs baseline: 1.4501x; 1.4501x over previous
//
#include <hip/hip_runtime.h>

#define NSEQ 4096
#define CHN 256

typedef __attribute__((ext_vector_type(8))) short short8;
typedef __attribute__((ext_vector_type(4))) float f32x4;
typedef __attribute__((ext_vector_type(4))) unsigned short us4;
typedef unsigned short u16;

// fp32 -> bf16 round-to-nearest-even
__device__ __forceinline__ u16 f2b(float f) {
  unsigned u = __builtin_bit_cast(unsigned, f);
  unsigned r = (u + 0x7fffu + ((u >> 16) & 1u)) >> 16;
  return (u16)r;
}
__device__ __forceinline__ float b2f(u16 h) {
  unsigned u = ((unsigned)h) << 16;
  return __builtin_bit_cast(float, u);
}

// ws layout in u16 elements
#define QH_OFF   0u          // [B][N][32]  theta^T hi (pre-scaled by log2e)
#define QL_OFF   524288u     // [B][N][32]  theta^T lo
#define KH_OFF   1048576u    // [B][N][32]  phi^T hi
#define KL_OFF   1572864u    // [B][N][32]  phi^T lo
#define V_OFF    2097152u    // [B][128][N] g
#define WQKH_OFF 4194304u    // [64][256]   (Wt*log2e | Wp) hi
#define WQKL_OFF 4210688u    // [64][256]   (Wt*log2e | Wp) lo
#define WG_OFF   4227072u    // [128][256]  Wg
#define WO_OFF   4259840u    // [256][128]  Wo

// ---------------- kernel 0: weight prep (fp32 -> bf16 / hi+lo) ----------------
__global__ __launch_bounds__(256) void prep_weights(
    const float* __restrict__ Wt, const float* __restrict__ Wp,
    const float* __restrict__ Wg, const float* __restrict__ Wo,
    u16* __restrict__ Wqkh, u16* __restrict__ Wqkl,
    u16* __restrict__ Wgb, u16* __restrict__ Wob) {
  int gid = blockIdx.x * 256 + threadIdx.x;  // 80 blocks -> 20480 threads
  if (gid < 4096) {                          // 64*256/4 float4 tasks, hi/lo split
    int row = gid >> 6;
    int c = (gid & 63) * 4;
    const float* src;
    float scale = 1.0f;
    if (row < 32) { src = Wt + row * 256; scale = 1.44269504088896340736f; }
    else          { src = Wp + (row - 32) * 256; }
    float4 v = *(const float4*)(src + c);
    float w0 = v.x * scale, w1 = v.y * scale, w2 = v.z * scale, w3 = v.w * scale;
    us4 hi = { f2b(w0), f2b(w1), f2b(w2), f2b(w3) };
    us4 lo = { f2b(w0 - b2f(hi[0])), f2b(w1 - b2f(hi[1])),
               f2b(w2 - b2f(hi[2])), f2b(w3 - b2f(hi[3])) };
    *(us4*)(Wqkh + row * 256 + c) = hi;
    *(us4*)(Wqkl + row * 256 + c) = lo;
  } else if (gid < 12288) {                  // Wg: 128*256/4 float4 tasks
    int g = (gid - 4096) * 4;
    float4 v = *(const float4*)(Wg + g);
    us4 o = { f2b(v.x), f2b(v.y), f2b(v.z), f2b(v.w) };
    *(us4*)(Wgb + g) = o;
  } else {                                   // Wo: 256*128/4 float4 tasks
    int g = (gid - 12288) * 4;
    float4 v = *(const float4*)(Wo + g);
    us4 o = { f2b(v.x), f2b(v.y), f2b(v.z), f2b(v.w) };
    *(us4*)(Wob + g) = o;
  }
}

// ---------------- kernel 1: QKV projection, 4-way output-slice split ----------------
// slice 0: theta (hi/lo), 1: phi (hi/lo), 2: g rows 0-63, 3: g rows 64-127.
// grid 1024 = 4 blocks/CU -> 16 waves/CU; slice in HIGH bits so all 4 slices of a
// tile share an XCD (x tile L2-resident).
__global__ __launch_bounds__(256, 4) void proj_qkv(
    const float* __restrict__ x,
    const u16* __restrict__ Wqkh, const u16* __restrict__ Wqkl,
    const u16* __restrict__ Wgb,
    u16* __restrict__ QbH, u16* __restrict__ QbL,
    u16* __restrict__ KbH, u16* __restrict__ KbL,
    u16* __restrict__ Vb) {
  int tid = threadIdx.x;
  int wave = tid >> 6, lane = tid & 63;
  int l15 = lane & 15, quad = lane >> 4;
  int slice = blockIdx.x >> 8;
  int tb = blockIdx.x & 255;
  int b = tb >> 6;
  int n0 = (tb & 63) * 64;
  int pos = n0 + wave * 16 + l15;
  const float* xb = x + (size_t)b * CHN * NSEQ + pos;
  int nbase = n0 + wave * 16 + quad * 4;

  if (slice < 2) {
    const u16* Wh = Wqkh + slice * 32 * 256;
    const u16* Wl = Wqkl + slice * 32 * 256;
    f32x4 acc[2];
    acc[0] = (f32x4){0.f, 0.f, 0.f, 0.f};
    acc[1] = (f32x4){0.f, 0.f, 0.f, 0.f};
#pragma unroll
    for (int kc = 0; kc < 8; kc++) {
      short8 ahi, alo;
#pragma unroll
      for (int j = 0; j < 8; j++) {
        float xv = xb[(size_t)(kc * 32 + quad * 8 + j) * NSEQ];
        u16 hi = f2b(xv);
        ahi[j] = (short)hi;
        alo[j] = (short)f2b(xv - b2f(hi));
      }
#pragma unroll
      for (int ot = 0; ot < 2; ot++) {
        size_t off = (size_t)(ot * 16 + l15) * 256 + kc * 32 + quad * 8;
        short8 bh = *(const short8*)(Wh + off);
        short8 bl = *(const short8*)(Wl + off);
        acc[ot] = __builtin_amdgcn_mfma_f32_16x16x32_bf16(alo, bh, acc[ot], 0, 0, 0);
        acc[ot] = __builtin_amdgcn_mfma_f32_16x16x32_bf16(ahi, bl, acc[ot], 0, 0, 0);
        acc[ot] = __builtin_amdgcn_mfma_f32_16x16x32_bf16(ahi, bh, acc[ot], 0, 0, 0);
      }
    }
    u16* Hp = (slice == 0) ? QbH : KbH;
    u16* Lp = (slice == 0) ? QbL : KbL;
#pragma unroll
    for (int ot = 0; ot < 2; ot++) {
#pragma unroll
      for (int r = 0; r < 4; r++) {
        float v = acc[ot][r];
        u16 hi = f2b(v);
        u16 lo = f2b(v - b2f(hi));
        size_t nrow = (size_t)(b * NSEQ + nbase + r) * 32 + ot * 16 + l15;
        Hp[nrow] = hi; Lp[nrow] = lo;
      }
    }
  } else {
    const u16* Wg2 = Wgb + (size_t)(slice - 2) * 64 * 256;
    f32x4 acc[4];
#pragma unroll
    for (int oi = 0; oi < 4; oi++) acc[oi] = (f32x4){0.f, 0.f, 0.f, 0.f};
#pragma unroll
    for (int kc = 0; kc < 8; kc++) {
      short8 ahi;
#pragma unroll
      for (int j = 0; j < 8; j++)
        ahi[j] = (short)f2b(xb[(size_t)(kc * 32 + quad * 8 + j) * NSEQ]);
#pragma unroll
      for (int oi = 0; oi < 4; oi++) {
        short8 bg = *(const short8*)(Wg2 + (size_t)(oi * 16 + l15) * 256 + kc * 32 + quad * 8);
        acc[oi] = __builtin_amdgcn_mfma_f32_16x16x32_bf16(ahi, bg, acc[oi], 0, 0, 0);
      }
    }
#pragma unroll
    for (int oi = 0; oi < 4; oi++) {
      int c = (slice - 2) * 64 + oi * 16 + l15;
      us4 pk = { f2b(acc[oi][0]), f2b(acc[oi][1]), f2b(acc[oi][2]), f2b(acc[oi][3]) };
      *(us4*)(Vb + (size_t)(b * 128 + c) * NSEQ + nbase) = pk;
    }
  }
}

// ---------------- kernel 2: fused flash attention + Wo + epilogue ----------------
// 512-thread blocks: 8 waves = 2 row-groups (32 Q rows each) x 4 key-splits
// (1024 keys each). In-block split-K combined through LDS. b = blockIdx&3 for
// XCD L2 affinity (K+V per batch = 1.5 MB, L2-resident).
__global__ __launch_bounds__(512, 2) void flash_attn(
    const u16* __restrict__ QbH, const u16* __restrict__ QbL,
    const u16* __restrict__ KbH, const u16* __restrict__ KbL,
    const u16* __restrict__ Vb, const u16* __restrict__ Wob,
    const float* __restrict__ x, const float* __restrict__ gammap,
    float* __restrict__ out) {
  // smem: region0 = P_lds [8][2][16][48] u16 (24576 B), aliased by A_lds [2][32][136]
  //       region1 = Comb [2][16][64] f32x4 (32768 B) @24576; CombL [2][2][64] f32 @57344
  __shared__ alignas(16) char smem[58368];
  u16 (*P_lds)[2][16][48] = (u16(*)[2][16][48])smem;
  u16 (*A_lds)[32][136]   = (u16(*)[32][136])smem;
  f32x4 (*Comb)[16][64]   = (f32x4(*)[16][64])(smem + 24576);
  float (*CombL)[2][64]   = (float(*)[2][64])(smem + 57344);

  int tid = threadIdx.x;
  int wave = tid >> 6, lane = tid & 63;
  int l15 = lane & 15, quad = lane >> 4;
  int sp = wave >> 1, rg = wave & 1;
  int b = blockIdx.x & 3;
  int tile = blockIdx.x >> 2;
  int n0 = tile * 64;
  int nqb = n0 + rg * 32;
  int ms = sp * 1024;

  short8 qh[2], ql[2];
#pragma unroll
  for (int nt = 0; nt < 2; nt++) {
    size_t qoff = (size_t)(b * NSEQ + nqb + nt * 16 + l15) * 32 + quad * 8;
    qh[nt] = *(const short8*)(QbH + qoff);
    ql[nt] = *(const short8*)(QbL + qoff);
  }
  const u16* KpH = KbH + (size_t)b * NSEQ * 32;
  const u16* KpL = KbL + (size_t)b * NSEQ * 32;
  const u16* Vp = Vb + (size_t)b * 128 * NSEQ + (size_t)l15 * NSEQ + quad * 8;

  f32x4 acc[2][8];
#pragma unroll
  for (int nt = 0; nt < 2; nt++)
#pragma unroll
    for (int vt = 0; vt < 8; vt++) acc[nt][vt] = (f32x4){0.f, 0.f, 0.f, 0.f};
  float lsum[2] = {0.f, 0.f};

  // prefetch chunk 0 of this wave's split
  short8 kh0 = *(const short8*)(KpH + (size_t)(ms + l15) * 32 + quad * 8);
  short8 kh1 = *(const short8*)(KpH + (size_t)(ms + 16 + l15) * 32 + quad * 8);
  short8 kl0 = *(const short8*)(KpL + (size_t)(ms + l15) * 32 + quad * 8);
  short8 kl1 = *(const short8*)(KpL + (size_t)(ms + 16 + l15) * 32 + quad * 8);
  short8 vf[8];
#pragma unroll
  for (int vt = 0; vt < 8; vt++) vf[vt] = *(const short8*)(Vp + (size_t)vt * 16 * NSEQ + ms);

  for (int ci = 0; ci < 32; ci++) {
    int mn = ms + (((ci + 1) & 31) << 5);  // next chunk (wraps harmlessly)
    short8 nkh0 = *(const short8*)(KpH + (size_t)(mn + l15) * 32 + quad * 8);
    short8 nkh1 = *(const short8*)(KpH + (size_t)(mn + 16 + l15) * 32 + quad * 8);
    short8 nkl0 = *(const short8*)(KpL + (size_t)(mn + l15) * 32 + quad * 8);
    short8 nkl1 = *(const short8*)(KpL + (size_t)(mn + 16 + l15) * 32 + quad * 8);
    short8 nvf[8];
#pragma unroll
    for (int vt = 0; vt < 8; vt++)
      nvf[vt] = *(const short8*)(Vp + (size_t)vt * 16 * NSEQ + mn);

    // S^T[mk][nq] per (kt key-half, nt row-tile), hi/lo split, small terms first
    f32x4 z = (f32x4){0.f, 0.f, 0.f, 0.f};
    f32x4 s[2][2];
#pragma unroll
    for (int nt = 0; nt < 2; nt++) {
      s[0][nt] = __builtin_amdgcn_mfma_f32_16x16x32_bf16(kl0, qh[nt], z, 0, 0, 0);
      s[0][nt] = __builtin_amdgcn_mfma_f32_16x16x32_bf16(kh0, ql[nt], s[0][nt], 0, 0, 0);
      s[0][nt] = __builtin_amdgcn_mfma_f32_16x16x32_bf16(kh0, qh[nt], s[0][nt], 0, 0, 0);
      s[1][nt] = __builtin_amdgcn_mfma_f32_16x16x32_bf16(kl1, qh[nt], z, 0, 0, 0);
      s[1][nt] = __builtin_amdgcn_mfma_f32_16x16x32_bf16(kh1, ql[nt], s[1][nt], 0, 0, 0);
      s[1][nt] = __builtin_amdgcn_mfma_f32_16x16x32_bf16(kh1, qh[nt], s[1][nt], 0, 0, 0);
    }
#pragma unroll
    for (int nt = 0; nt < 2; nt++) {
#pragma unroll
      for (int kt = 0; kt < 2; kt++) {
        us4 p;
#pragma unroll
        for (int r = 0; r < 4; r++) {
          float e = exp2f(s[kt][nt][r]);
          lsum[nt] += e;
          p[r] = f2b(e);
        }
        *(us4*)&P_lds[wave][nt][l15][kt * 16 + quad * 4] = p;
      }
    }
    short8 af[2];
#pragma unroll
    for (int nt = 0; nt < 2; nt++)
      af[nt] = *(const short8*)&P_lds[wave][nt][l15][quad * 8];
#pragma unroll
    for (int nt = 0; nt < 2; nt++)
#pragma unroll
      for (int vt = 0; vt < 8; vt++)
        acc[nt][vt] = __builtin_amdgcn_mfma_f32_16x16x32_bf16(af[nt], vf[vt], acc[nt][vt], 0, 0, 0);

    kh0 = nkh0; kh1 = nkh1; kl0 = nkl0; kl1 = nkl1;
#pragma unroll
    for (int vt = 0; vt < 8; vt++) vf[vt] = nvf[vt];
  }

  // ---- in-block split-K combine (3 sequential stages through LDS) ----
  for (int s = 1; s < 4; s++) {
    if (sp == s) {
#pragma unroll
      for (int nt = 0; nt < 2; nt++)
#pragma unroll
        for (int vt = 0; vt < 8; vt++)
          Comb[rg][nt * 8 + vt][lane] = acc[nt][vt];
      CombL[rg][0][lane] = lsum[0];
      CombL[rg][1][lane] = lsum[1];
    }
    __syncthreads();
    if (sp == 0) {
#pragma unroll
      for (int nt = 0; nt < 2; nt++)
#pragma unroll
        for (int vt = 0; vt < 8; vt++) {
          f32x4 c = Comb[rg][nt * 8 + vt][lane];
          acc[nt][vt] += c;
        }
      lsum[0] += CombL[rg][0][lane];
      lsum[1] += CombL[rg][1][lane];
    }
    __syncthreads();
  }

  // ---- normalize + transpose to A_lds (waves 0,1 hold full sums) ----
  if (sp == 0) {
#pragma unroll
    for (int nt = 0; nt < 2; nt++) {
      lsum[nt] += __shfl_xor(lsum[nt], 16);
      lsum[nt] += __shfl_xor(lsum[nt], 32);
      float rinv = 1.0f / lsum[nt];
#pragma unroll
      for (int r = 0; r < 4; r++) {
        float rr = __shfl(rinv, quad * 4 + r);
#pragma unroll
        for (int vt = 0; vt < 8; vt++)
          A_lds[rg][nt * 16 + quad * 4 + r][vt * 16 + l15] = f2b(acc[nt][vt][r] * rr);
      }
    }
  }
  __syncthreads();

  // ---- Wo GEMM + epilogue: waves 0-3, 16 positions each ----
  if (wave < 4) {
    int pg = wave;
    short8 bfr[4];
#pragma unroll
    for (int kc = 0; kc < 4; kc++)
      bfr[kc] = *(const short8*)&A_lds[pg >> 1][(pg & 1) * 16 + l15][kc * 32 + quad * 8];
    f32x4 oacc[16];
#pragma unroll
    for (int mt = 0; mt < 16; mt++) oacc[mt] = (f32x4){0.f, 0.f, 0.f, 0.f};
#pragma unroll
    for (int mt = 0; mt < 16; mt++) {
#pragma unroll
      for (int kc = 0; kc < 4; kc++) {
        short8 wf = *(const short8*)(Wob + (size_t)(mt * 16 + l15) * 128 + kc * 32 + quad * 8);
        oacc[mt] = __builtin_amdgcn_mfma_f32_16x16x32_bf16(wf, bfr[kc], oacc[mt], 0, 0, 0);
      }
    }
    float gamma = *gammap;
#pragma unroll
    for (int mt = 0; mt < 16; mt++) {
#pragma unroll
      for (int r = 0; r < 4; r++) {
        int oc = mt * 16 + quad * 4 + r;
        size_t idx = ((size_t)b * CHN + oc) * NSEQ + n0 + pg * 16 + l15;
        out[idx] = gamma * oacc[mt][r] + x[idx];
      }
    }
  }
}

extern "C" void kernel_launch(void* const* d_in, const int* in_sizes, int n_in,
                              void* d_out, int out_size, void* d_ws, size_t ws_size,
                              hipStream_t stream) {
  const float* x  = (const float*)d_in[0];
  const float* Wt = (const float*)d_in[1];
  const float* Wp = (const float*)d_in[2];
  const float* Wg = (const float*)d_in[3];
  const float* Wo = (const float*)d_in[4];
  const float* gm = (const float*)d_in[5];
  float* out = (float*)d_out;
  u16* ws = (u16*)d_ws;
  u16* QbH  = ws + QH_OFF;
  u16* QbL  = ws + QL_OFF;
  u16* KbH  = ws + KH_OFF;
  u16* KbL  = ws + KL_OFF;
  u16* Vb   = ws + V_OFF;
  u16* Wqkh = ws + WQKH_OFF;
  u16* Wqkl = ws + WQKL_OFF;
  u16* Wgb  = ws + WG_OFF;
  u16* Wob  = ws + WO_OFF;

  prep_weights<<<80, 256, 0, stream>>>(Wt, Wp, Wg, Wo, Wqkh, Wqkl, Wgb, Wob);
  proj_qkv<<<1024, 256, 0, stream>>>(x, Wqkh, Wqkl, Wgb, QbH, QbL, KbH, KbL, Vb);
  flash_attn<<<256, 512, 0, stream>>>(QbH, QbL, KbH, KbL, Vb, Wob, x, gm, out);
}